// Round 1
// baseline (973.042 us; speedup 1.0000x reference)
//
#include <hip/hip_runtime.h>
#include <math.h>

#define BS      4096
#define DM      256
#define DINNER  2048
#define DSTATE  16
// proj width = DT_RANK + 2*DSTATE = 48
// h row per batch: DINNER*DSTATE = 32768 floats = 8192 float4

__device__ __forceinline__ float silu_f(float x) {
    return x / (1.f + __expf(-x));
}

__device__ __forceinline__ float softplus_f(float x) {
    if (x > 20.f) return x;
    if (x < -20.f) return __expf(x);
    return __logf(1.f + __expf(x));
}

__global__ void a_precompute_kernel(const float* __restrict__ A_log,
                                    float* __restrict__ A) {
    int i = blockIdx.x * 256 + threadIdx.x;   // 32768 total
    A[i] = -__expf(A_log[i]);
}

__global__ __launch_bounds__(256)
void flow_main_kernel(const float* __restrict__ bbox,
                      const float* __restrict__ h_in,
                      const float* __restrict__ flow_embed,
                      const float* __restrict__ W_in,
                      const float* __restrict__ b_in,
                      const float* __restrict__ W_dt,
                      const float* __restrict__ b_dt,
                      const float* __restrict__ W_flow,
                      const float* __restrict__ Aptr,  // -exp(A_log) if a_ready, else A_log
                      int a_ready,
                      const float* __restrict__ Dvec,
                      const float* __restrict__ W_out,
                      const float* __restrict__ b_out,
                      float* __restrict__ out,
                      float* __restrict__ h_out)
{
    __shared__ __align__(16) float fe_s[DM];
    __shared__ float proj_s[48];
    __shared__ float pp_s[48][4];
    __shared__ float dt_s[DINNER];
    __shared__ float edt_s[DINNER];
    __shared__ float ye_s[DINNER];
    __shared__ float rs_s[DINNER];
    __shared__ float red_s[4][4];

    const int b = blockIdx.x;
    const int t = threadIdx.x;

    // ---- phase 0: flow_embed row to LDS, proj_f = fe @ W_flow.T (48 outputs)
    fe_s[t] = flow_embed[b * DM + t];
    __syncthreads();

    if (t < 192) {
        const int k = t >> 2, p = t & 3;
        const float4* wf  = (const float4*)(W_flow + k * DM);
        const float4* fe4 = (const float4*)fe_s;
        float s = 0.f;
        #pragma unroll
        for (int i = 0; i < 16; ++i) {
            float4 w = wf[p * 16 + i];
            float4 f = fe4[p * 16 + i];
            s += w.x * f.x + w.y * f.y + w.z * f.z + w.w * f.w;
        }
        pp_s[k][p] = s;
    }
    __syncthreads();
    if (t < 48)
        proj_s[t] = pp_s[t][0] + pp_s[t][1] + pp_s[t][2] + pp_s[t][3];
    __syncthreads();

    // ---- phase 1: per-d scalars: dt (softplus), e=silu, cache dt, e*dt, D*e, silu(r)
    float dl[16];
    #pragma unroll
    for (int k = 0; k < 16; ++k) dl[k] = proj_s[k];
    const float4 bb = ((const float4*)bbox)[b];

    #pragma unroll
    for (int i = 0; i < 8; ++i) {
        const int d = t + i * 256;
        float4 wi = ((const float4*)W_in)[d];
        float e = fmaf(bb.x, wi.x, fmaf(bb.y, wi.y, fmaf(bb.z, wi.z, bb.w * wi.w))) + b_in[d];
        e = silu_f(e);
        float4 wr = ((const float4*)W_in)[DINNER + d];
        float r = fmaf(bb.x, wr.x, fmaf(bb.y, wr.y, fmaf(bb.z, wr.z, bb.w * wr.w))) + b_in[DINNER + d];
        const float rs = silu_f(r);

        const float4* wd = (const float4*)(W_dt + d * 16);
        float s = 0.f;
        #pragma unroll
        for (int j = 0; j < 4; ++j) {
            float4 w = wd[j];
            s += w.x * dl[j * 4 + 0] + w.y * dl[j * 4 + 1] +
                 w.z * dl[j * 4 + 2] + w.w * dl[j * 4 + 3];
        }
        const float dt = softplus_f(s + b_dt[d]);

        dt_s[d]  = dt;
        edt_s[d] = e * dt;
        ye_s[d]  = Dvec[d] * e;
        rs_s[d]  = rs;
    }
    __syncthreads();

    // ---- main loop: stream the 128 KB h row as float4; thread owns (d, n-quad)
    const int nq = t & 3;
    float Bq[4], Cq[4];
    #pragma unroll
    for (int j = 0; j < 4; ++j) {
        Bq[j] = proj_s[16 + nq * 4 + j];
        Cq[j] = proj_s[32 + nq * 4 + j];
    }

    const float4* __restrict__ hin4  = (const float4*)(h_in + (size_t)b * 32768);
    float4* __restrict__       hout4 = (float4*)(h_out + (size_t)b * 32768);
    const float4* __restrict__ A4    = (const float4*)Aptr;

    float acc0 = 0.f, acc1 = 0.f, acc2 = 0.f, acc3 = 0.f;

    #pragma unroll 2
    for (int it = 0; it < 32; ++it) {
        const int idx = it * 256 + t;     // float4 index in row; flat = idx*4
        const int d   = idx >> 2;
        float4 h = hin4[idx];
        float4 a = A4[idx];
        if (!a_ready) {                   // uniform branch: A given as A_log
            a.x = -__expf(a.x); a.y = -__expf(a.y);
            a.z = -__expf(a.z); a.w = -__expf(a.w);
        }
        const float dt  = dt_s[d];
        const float edt = edt_s[d];
        float4 hn;
        hn.x = fmaf(h.x, __expf(dt * a.x), edt * Bq[0]);
        hn.y = fmaf(h.y, __expf(dt * a.y), edt * Bq[1]);
        hn.z = fmaf(h.z, __expf(dt * a.z), edt * Bq[2]);
        hn.w = fmaf(h.w, __expf(dt * a.w), edt * Bq[3]);
        hout4[idx] = hn;

        float ys = hn.x * Cq[0] + hn.y * Cq[1] + hn.z * Cq[2] + hn.w * Cq[3];
        ys += __shfl_xor(ys, 1, 64);
        ys += __shfl_xor(ys, 2, 64);      // all 4 lanes of the d-group hold full sum
        if (nq == 0) {
            const float y = (ys + ye_s[d]) * rs_s[d];
            acc0 = fmaf(y, W_out[d],          acc0);
            acc1 = fmaf(y, W_out[DINNER + d], acc1);
            acc2 = fmaf(y, W_out[2 * DINNER + d], acc2);
            acc3 = fmaf(y, W_out[3 * DINNER + d], acc3);
        }
    }

    // ---- out reduction: only nq==0 lanes hold nonzero partials
    #pragma unroll
    for (int off = 4; off < 64; off <<= 1) {
        acc0 += __shfl_xor(acc0, off, 64);
        acc1 += __shfl_xor(acc1, off, 64);
        acc2 += __shfl_xor(acc2, off, 64);
        acc3 += __shfl_xor(acc3, off, 64);
    }
    const int wave = t >> 6;
    if ((t & 63) == 0) {
        red_s[wave][0] = acc0; red_s[wave][1] = acc1;
        red_s[wave][2] = acc2; red_s[wave][3] = acc3;
    }
    __syncthreads();
    if (t == 0) {
        #pragma unroll
        for (int j = 0; j < 4; ++j) {
            out[b * 4 + j] = red_s[0][j] + red_s[1][j] + red_s[2][j] + red_s[3][j]
                           + b_out[j];
        }
    }
}

extern "C" void kernel_launch(void* const* d_in, const int* in_sizes, int n_in,
                              void* d_out, int out_size, void* d_ws, size_t ws_size,
                              hipStream_t stream) {
    const float* bbox   = (const float*)d_in[0];
    const float* h_in   = (const float*)d_in[1];
    const float* fe     = (const float*)d_in[2];
    const float* W_in   = (const float*)d_in[3];
    const float* b_in   = (const float*)d_in[4];
    const float* W_dt   = (const float*)d_in[5];
    const float* b_dt   = (const float*)d_in[6];
    const float* W_flow = (const float*)d_in[7];
    const float* A_log  = (const float*)d_in[8];
    const float* Dvec   = (const float*)d_in[9];
    const float* W_out  = (const float*)d_in[10];
    const float* b_out  = (const float*)d_in[11];

    float* out   = (float*)d_out;
    float* h_out = out + BS * 4;

    const size_t a_bytes = (size_t)DINNER * DSTATE * sizeof(float);  // 128 KB
    const int a_ready = (ws_size >= a_bytes) ? 1 : 0;
    const float* Aptr = A_log;
    if (a_ready) {
        float* Aws = (float*)d_ws;
        hipLaunchKernelGGL(a_precompute_kernel, dim3((DINNER * DSTATE) / 256),
                           dim3(256), 0, stream, A_log, Aws);
        Aptr = Aws;
    }

    hipLaunchKernelGGL(flow_main_kernel, dim3(BS), dim3(256), 0, stream,
                       bbox, h_in, fe, W_in, b_in, W_dt, b_dt, W_flow,
                       Aptr, a_ready, Dvec, W_out, b_out, out, h_out);
}